// Round 15
// baseline (224.414 us; speedup 1.0000x reference)
//
#include <hip/hip_runtime.h>

typedef __bf16 bf16;
typedef bf16 bf16x4 __attribute__((ext_vector_type(4)));
typedef bf16 bf16x8 __attribute__((ext_vector_type(8)));
typedef float f32x4 __attribute__((ext_vector_type(4)));

#define MFMA16(A, B, C) __builtin_amdgcn_mfma_f32_16x16x32_bf16(A, B, C, 0, 0, 0)
#define NEG_BIG -30000.0f
#define LOG2E 1.44269504089f

// async 16B global->LDS: lds dest = wave-uniform base + lane*16
#define GLOAD_LDS16(gptr, lptr)                                                \
    __builtin_amdgcn_global_load_lds(                                          \
        (__attribute__((address_space(1))) void*)(gptr),                       \
        (__attribute__((address_space(3))) void*)(lptr), 16, 0, 0)

// XOR swizzle for 64-elem bf16 rows (chunk = 8 elems = 16B)
#define SW(r, c8) ((r) * 64 + (((((c8) >> 3) ^ ((r) & 7))) << 3))

// ---------------------------------------------------------------------------
__global__ void mark_k(float* __restrict__ out, float val, int n) {
    int i = blockIdx.x * 256 + threadIdx.x;
    if (i < n) out[i] = val;
}

// ---------------------------------------------------------------------------
__global__ __launch_bounds__(256) void cvt_x_k(const float* __restrict__ src,
                                               bf16* __restrict__ dst, int n) {
    int i = (blockIdx.x * 256 + threadIdx.x) * 8;
    if (i >= n) return;
    float4 a = *(const float4*)&src[i];
    float4 b = *(const float4*)&src[i + 4];
    bf16x8 w;
    w[0] = (bf16)a.x; w[1] = (bf16)a.y; w[2] = (bf16)a.z; w[3] = (bf16)a.w;
    w[4] = (bf16)b.x; w[5] = (bf16)b.y; w[6] = (bf16)b.z; w[7] = (bf16)b.w;
    *(bf16x8*)&dst[i] = w;
}

// ---------------------------------------------------------------------------
__global__ void prep_mask_k(const int* __restrict__ mask, float* __restrict__ am) {
    int i = blockIdx.x * 256 + threadIdx.x;   // 0..4095
    am[i] = (mask[i] != 0) ? 0.0f : NEG_BIG;
}

// ---------------------------------------------------------------------------
__global__ __launch_bounds__(256) void transpose_cvt_tiled(
    const float* __restrict__ src, bf16* __restrict__ dst, int R, int C) {
    __shared__ float t[32][33];
    int tid = threadIdx.x, tx = tid & 31, ty = tid >> 5;
    int bx = blockIdx.x * 32, by = blockIdx.y * 32;
#pragma unroll
    for (int i = 0; i < 4; ++i) {
        int row = by + ty + i * 8;
        t[ty + i * 8][tx] = src[(size_t)row * C + bx + tx];
    }
    __syncthreads();
#pragma unroll
    for (int i = 0; i < 4; ++i) {
        int outrow = bx + ty + i * 8;
        dst[(size_t)outrow * R + by + tx] = (bf16)t[tx][ty + i * 8];
    }
}

// ---------------------------------------------------------------------------
// QKV GEMM v3: 128x128 tile, BK=64 (12 iters), XOR-swizzled async staging,
// SWAPPED MFMA operands -> D transposed: lane holds 4 consecutive out-cols.
// Q/K stores bf16x4-packed; V scatter. Q pre-scaled by 0.125*log2e.
// ---------------------------------------------------------------------------
__global__ __launch_bounds__(256) void gemm_qkv_v3(
    const bf16* __restrict__ A, const bf16* __restrict__ B,
    const float* __restrict__ bias, bf16* __restrict__ Qh,
    bf16* __restrict__ Kh, bf16* __restrict__ Vth) {
    __shared__ __align__(16) bf16 As[128 * 64];   // 16 KB
    __shared__ __align__(16) bf16 Bs[128 * 64];   // 16 KB
    int tid = threadIdx.x, lane = tid & 63, wave = tid >> 6;
    int quad = lane >> 4, l16 = lane & 15;
    int wr = wave >> 1, wc = wave & 1;
    int m0 = blockIdx.y * 128, n0 = blockIdx.x * 128;
    const int K = 768;
    const f32x4 fz = {0.f, 0.f, 0.f, 0.f};
    f32x4 acc[4][4];   // [nj][mi], transposed D
#pragma unroll
    for (int nj = 0; nj < 4; ++nj)
#pragma unroll
        for (int mi = 0; mi < 4; ++mi) acc[nj][mi] = fz;
    const bf16* Ablk = A + (size_t)m0 * K;
    const bf16* Bblk = B + (size_t)n0 * K;
    int lrow8 = lane >> 3;                          // 0..7
    int sc = ((lane & 7) ^ (lrow8 & 7)) << 3;       // swizzled source chunk

    for (int k0 = 0; k0 < K; k0 += 64) {
        __syncthreads();
#pragma unroll
        for (int i = 0; i < 4; ++i) {
            int r0 = i * 32 + wave * 8;             // wave-uniform row base
            int row = r0 + lrow8;
            GLOAD_LDS16(&Ablk[(size_t)row * K + k0 + sc], &As[r0 * 64]);
            GLOAD_LDS16(&Bblk[(size_t)row * K + k0 + sc], &Bs[r0 * 64]);
        }
        __syncthreads();
        bf16x8 af[2][4], bfv[2][4];
#pragma unroll
        for (int t = 0; t < 4; ++t)
#pragma unroll
            for (int hh = 0; hh < 2; ++hh) {
                af[hh][t]  = *(const bf16x8*)&As[SW(wr * 64 + t * 16 + l16, hh * 32 + quad * 8)];
                bfv[hh][t] = *(const bf16x8*)&Bs[SW(wc * 64 + t * 16 + l16, hh * 32 + quad * 8)];
            }
#pragma unroll
        for (int nj = 0; nj < 4; ++nj)
#pragma unroll
            for (int mi = 0; mi < 4; ++mi) {
                acc[nj][mi] = MFMA16(bfv[0][nj], af[0][mi], acc[nj][mi]);
                acc[nj][mi] = MFMA16(bfv[1][nj], af[1][mi], acc[nj][mi]);
            }
    }

    // Epilogue (transposed D): out-col = n0+wc*64+nj*16+quad*4+r (consecutive
    // over r), out-row(x-row) = m0+wr*64+mi*16+l16.
#pragma unroll
    for (int nj = 0; nj < 4; ++nj) {
        int c0 = n0 + wc * 64 + nj * 16 + quad * 4;
        float4 bv4 = *(const float4*)&bias[c0];
        float bv[4] = {bv4.x, bv4.y, bv4.z, bv4.w};
        int which = c0 / 768, rr = c0 % 768;
        int h = rr >> 6, d0 = rr & 63;
#pragma unroll
        for (int mi = 0; mi < 4; ++mi) {
            int xrow = m0 + wr * 64 + mi * 16 + l16;
            int b = xrow >> 11, l = xrow & 2047;
            size_t bh = (size_t)(b * 12 + h);
            if (which == 0) {
                bf16x4 v;
#pragma unroll
                for (int r = 0; r < 4; ++r)
                    v[r] = (bf16)((acc[nj][mi][r] + bv[r]) * (0.125f * LOG2E));
                *(bf16x4*)&Qh[(bh * 2048 + l) * 64 + d0] = v;
            } else if (which == 1) {
                bf16x4 v;
#pragma unroll
                for (int r = 0; r < 4; ++r) v[r] = (bf16)(acc[nj][mi][r] + bv[r]);
                *(bf16x4*)&Kh[(bh * 2048 + l) * 64 + d0] = v;
            } else {
#pragma unroll
                for (int r = 0; r < 4; ++r)
                    Vth[(bh * 64 + d0 + r) * 2048 + l] = (bf16)(acc[nj][mi][r] + bv[r]);
            }
        }
    }
}

// ---------------------------------------------------------------------------
// Out-projection GEMM v3 (unchanged): 128M x 64N, 128 thr, grid (12,32).
// ---------------------------------------------------------------------------
__global__ __launch_bounds__(128) void gemm_out_v3(
    const bf16* __restrict__ A, const bf16* __restrict__ B,
    const float* __restrict__ bias, float* __restrict__ C) {
    __shared__ __align__(16) bf16 As[128 * 32];
    __shared__ __align__(16) bf16 Bs[64 * 32];
    int tid = threadIdx.x, lane = tid & 63, wave = tid >> 6;
    int quad = lane >> 4, l16 = lane & 15;
    int m0 = blockIdx.y * 128, n0 = blockIdx.x * 64;
    const int K = 768, N = 768;
    const f32x4 fz = {0.f, 0.f, 0.f, 0.f};
    f32x4 acc[4][4];
#pragma unroll
    for (int mi = 0; mi < 4; ++mi)
#pragma unroll
        for (int nj = 0; nj < 4; ++nj) acc[mi][nj] = fz;
    const bf16* Ablk = A + (size_t)m0 * K;
    const bf16* Bblk = B + (size_t)n0 * K;
    int grow = tid >> 2, gcol = (tid & 3) * 8;

    for (int k0 = 0; k0 < K; k0 += 32) {
        __syncthreads();
#pragma unroll
        for (int i = 0; i < 4; ++i)
            GLOAD_LDS16(&Ablk[(size_t)(i * 32 + grow) * K + k0 + gcol],
                        &As[i * 1024 + wave * 512]);
#pragma unroll
        for (int i = 0; i < 2; ++i)
            GLOAD_LDS16(&Bblk[(size_t)(i * 32 + grow) * K + k0 + gcol],
                        &Bs[i * 1024 + wave * 512]);
        __syncthreads();
        bf16x8 af[4], bfv[4];
#pragma unroll
        for (int t = 0; t < 4; ++t) {
            af[t]  = *(const bf16x8*)&As[(wave * 64 + t * 16 + l16) * 32 + quad * 8];
            bfv[t] = *(const bf16x8*)&Bs[(t * 16 + l16) * 32 + quad * 8];
        }
#pragma unroll
        for (int mi = 0; mi < 4; ++mi)
#pragma unroll
            for (int nj = 0; nj < 4; ++nj)
                acc[mi][nj] = MFMA16(af[mi], bfv[nj], acc[mi][nj]);
    }

#pragma unroll
    for (int nj = 0; nj < 4; ++nj) {
        int col = n0 + nj * 16 + l16;
        float bv = bias[col];
#pragma unroll
        for (int mi = 0; mi < 4; ++mi)
#pragma unroll
            for (int r = 0; r < 4; ++r) {
                int row = m0 + wave * 64 + mi * 16 + quad * 4 + r;
                C[(size_t)row * N + col] = acc[mi][nj][r] + bv;
            }
    }
}

// ---------------------------------------------------------------------------
// Flash attention v5 = proven v3 structure (manual staging, LDS maskS, 1
// barrier/iter) + exp2-domain softmax (Q pre-scaled by 0.125*log2e).
// ---------------------------------------------------------------------------
#define PLD 72

__global__ __launch_bounds__(128) void flash_attn(
    const bf16* __restrict__ Q, const bf16* __restrict__ K,
    const bf16* __restrict__ V, const int* __restrict__ mask,
    bf16* __restrict__ ctx) {
    __shared__ __align__(16) bf16 Ks[2][64 * 64];
    __shared__ __align__(16) bf16 Vs[2][64 * 64];
    __shared__ __align__(16) bf16 Ps[2][16 * PLD];
    __shared__ float maskS[2048];

    int tid = threadIdx.x, lane = tid & 63, wave = tid >> 6;
    int quad = lane >> 4, l16 = lane & 15;
    int bh = blockIdx.y, b = bh / 12;
    int q0 = blockIdx.x * 64 + wave * 32;

    bf16x8 aq[2][2];
#pragma unroll
    for (int qt = 0; qt < 2; ++qt) {
        const bf16* Qp = Q + ((size_t)bh * 2048 + q0 + qt * 16 + l16) * 64;
        aq[qt][0] = *(const bf16x8*)(Qp + quad * 8);
        aq[qt][1] = *(const bf16x8*)(Qp + 32 + quad * 8);
    }

    const int* mrow = mask + b * 2048;
#pragma unroll
    for (int i = 0; i < 16; ++i) {
        int idx = i * 128 + tid;
        maskS[idx] = (mrow[idx] != 0) ? 0.0f : NEG_BIG;
    }

    const f32x4 fz = {0.f, 0.f, 0.f, 0.f};
    f32x4 o[2][4];
    float m_i[2], l_i[2];
#pragma unroll
    for (int qt = 0; qt < 2; ++qt) {
        m_i[qt] = NEG_BIG; l_i[qt] = 0.f;
#pragma unroll
        for (int dt = 0; dt < 4; ++dt) o[qt][dt] = fz;
    }

    int srow = tid >> 3;
    int sc8  = (tid & 7) * 8;
    const bf16* Kbase = K + (size_t)bh * 2048 * 64;
    const bf16* Vbase = V + (size_t)bh * 64 * 2048;

#pragma unroll
    for (int i = 0; i < 4; ++i) {
        int row = srow + i * 16;
        *(bf16x8*)&Ks[0][SW(row, sc8)] =
            *(const bf16x8*)&Kbase[(size_t)row * 64 + sc8];
        *(bf16x8*)&Vs[0][SW(row, sc8)] =
            *(const bf16x8*)&Vbase[(size_t)row * 2048 + sc8];
    }

    int p = 0;
    for (int kb = 0; kb < 2048; kb += 64) {
        __syncthreads();

        if (kb + 64 < 2048) {
            int nb = kb + 64;
#pragma unroll
            for (int i = 0; i < 4; ++i) {
                int row = srow + i * 16;
                *(bf16x8*)&Ks[1 - p][SW(row, sc8)] =
                    *(const bf16x8*)&Kbase[(size_t)(nb + row) * 64 + sc8];
                *(bf16x8*)&Vs[1 - p][SW(row, sc8)] =
                    *(const bf16x8*)&Vbase[(size_t)row * 2048 + nb + sc8];
            }
        }

        f32x4 s[2][4];
#pragma unroll
        for (int ct = 0; ct < 4; ++ct) {
            int krow = ct * 16 + l16;
            bf16x8 kf0 = *(const bf16x8*)&Ks[p][SW(krow, quad * 8)];
            bf16x8 kf1 = *(const bf16x8*)&Ks[p][SW(krow, 32 + quad * 8)];
#pragma unroll
            for (int qt = 0; qt < 2; ++qt) {
                f32x4 t = fz;
                t = MFMA16(kf0, aq[qt][0], t);
                t = MFMA16(kf1, aq[qt][1], t);
                s[qt][ct] = t;
            }
        }

#pragma unroll
        for (int ct = 0; ct < 4; ++ct) {
            const float* mk = &maskS[kb + ct * 16 + quad * 4];
            float4 mv = *(const float4*)mk;
            float ma[4] = {mv.x, mv.y, mv.z, mv.w};
#pragma unroll
            for (int qt = 0; qt < 2; ++qt)
#pragma unroll
                for (int r = 0; r < 4; ++r) s[qt][ct][r] += ma[r];
        }

        float alpha[2];
#pragma unroll
        for (int qt = 0; qt < 2; ++qt) {
            float mx = NEG_BIG;
#pragma unroll
            for (int ct = 0; ct < 4; ++ct)
#pragma unroll
                for (int r = 0; r < 4; ++r) mx = fmaxf(mx, s[qt][ct][r]);
            mx = fmaxf(mx, __shfl_xor(mx, 16));
            mx = fmaxf(mx, __shfl_xor(mx, 32));
            float nm = fmaxf(m_i[qt], mx);
            alpha[qt] = exp2f(m_i[qt] - nm);
            m_i[qt] = nm;
            float sum = 0.f;
#pragma unroll
            for (int ct = 0; ct < 4; ++ct)
#pragma unroll
                for (int r = 0; r < 4; ++r) {
                    float pv = exp2f(s[qt][ct][r] - nm);
                    s[qt][ct][r] = pv;
                    sum += pv;
                }
            sum += __shfl_xor(sum, 16);
            sum += __shfl_xor(sum, 32);
            l_i[qt] = l_i[qt] * alpha[qt] + sum;
        }

#pragma unroll
        for (int qt = 0; qt < 2; ++qt) {
            float ab[4];
#pragma unroll
            for (int r = 0; r < 4; ++r)
                ab[r] = __shfl(alpha[qt], (lane & 48) | (quad * 4 + r));
#pragma unroll
            for (int dt = 0; dt < 4; ++dt)
#pragma unroll
                for (int r = 0; r < 4; ++r) o[qt][dt][r] *= ab[r];
        }

        bf16x8 vf[2][4];
#pragma unroll
        for (int ks = 0; ks < 2; ++ks)
#pragma unroll
            for (int dt = 0; dt < 4; ++dt)
                vf[ks][dt] = *(const bf16x8*)&Vs[p][SW(dt * 16 + l16, ks * 32 + quad * 8)];

#pragma unroll
        for (int qt = 0; qt < 2; ++qt) {
#pragma unroll
            for (int ct = 0; ct < 4; ++ct) {
                bf16x4 pk;
#pragma unroll
                for (int r = 0; r < 4; ++r) pk[r] = (bf16)s[qt][ct][r];
                *(bf16x4*)&Ps[wave][l16 * PLD + ct * 16 + quad * 4] = pk;
            }
#pragma unroll
            for (int ks = 0; ks < 2; ++ks) {
                bf16x8 ap = *(const bf16x8*)&Ps[wave][l16 * PLD + ks * 32 + quad * 8];
#pragma unroll
                for (int dt = 0; dt < 4; ++dt)
                    o[qt][dt] = MFMA16(ap, vf[ks][dt], o[qt][dt]);
            }
        }
        p ^= 1;
    }

    int h = bh % 12;
#pragma unroll
    for (int qt = 0; qt < 2; ++qt) {
        float linv[4];
#pragma unroll
        for (int r = 0; r < 4; ++r)
            linv[r] = 1.0f / __shfl(l_i[qt], (lane & 48) | (quad * 4 + r));
#pragma unroll
        for (int dt = 0; dt < 4; ++dt)
#pragma unroll
            for (int r = 0; r < 4; ++r) {
                int qrow = q0 + qt * 16 + quad * 4 + r;
                ctx[((size_t)b * 2048 + qrow) * 768 + h * 64 + dt * 16 + l16] =
                    (bf16)(o[qt][dt][r] * linv[r]);
            }
    }
}

// ---------------------------------------------------------------------------
extern "C" void kernel_launch(void* const* d_in, const int* in_sizes, int n_in,
                              void* d_out, int out_size, void* d_ws, size_t ws_size,
                              hipStream_t stream) {
    float* out = (float*)d_out;

    const float* x = nullptr; const int* mask = nullptr;
    const float* w_qkv = nullptr; const float* b_qkv = nullptr;
    const float* w_out = nullptr; const float* b_out = nullptr;
    int found = 0;
    for (int i = 0; i < n_in; ++i) {
        switch (in_sizes[i]) {
            case 3145728: x     = (const float*)d_in[i]; found |= 1;  break;
            case 4096:    mask  = (const int*)  d_in[i]; found |= 2;  break;
            case 1769472: w_qkv = (const float*)d_in[i]; found |= 4;  break;
            case 2304:    b_qkv = (const float*)d_in[i]; found |= 8;  break;
            case 589824:  w_out = (const float*)d_in[i]; found |= 16; break;
            case 768:     b_out = (const float*)d_in[i]; found |= 32; break;
        }
    }
    if (found != 63) {
        mark_k<<<(out_size + 255) / 256, 256, 0, stream>>>(
            out, 200.0f + (float)found, out_size);
        return;
    }

    const int M = 4096, D = 768, N3 = 2304;
    const size_t HEADS_ELEMS = (size_t)24 * 2048 * 64;

    bf16* ws    = (bf16*)d_ws;
    bf16* Kh    = ws;
    bf16* Vth   = Kh + HEADS_ELEMS;
    bf16* ctx   = Vth + HEADS_ELEMS;
    bf16* wqkvT = ctx + (size_t)M * D;
    bf16* woutT = wqkvT + (size_t)N3 * D;
    bf16* Qh    = (bf16*)d_out;
    bf16* xb    = (bf16*)d_out + HEADS_ELEMS;

    cvt_x_k<<<(M * D / 8 + 255) / 256, 256, 0, stream>>>(x, xb, M * D);
    transpose_cvt_tiled<<<dim3(2304 / 32, 768 / 32), 256, 0, stream>>>(
        w_qkv, wqkvT, 768, 2304);
    transpose_cvt_tiled<<<dim3(768 / 32, 768 / 32), 256, 0, stream>>>(
        w_out, woutT, 768, 768);

    gemm_qkv_v3<<<dim3(N3 / 128, M / 128), 256, 0, stream>>>(
        xb, wqkvT, b_qkv, Qh, Kh, Vth);

    flash_attn<<<dim3(2048 / 64, 24), 128, 0, stream>>>(Qh, Kh, Vth, mask, ctx);

    gemm_out_v3<<<dim3(D / 64, M / 128), 128, 0, stream>>>(
        ctx, woutT, b_out, out);
}

// Round 16
// 208.072 us; speedup vs baseline: 1.0785x; 1.0785x over previous
//
#include <hip/hip_runtime.h>

typedef __bf16 bf16;
typedef bf16 bf16x4 __attribute__((ext_vector_type(4)));
typedef bf16 bf16x8 __attribute__((ext_vector_type(8)));
typedef float f32x4 __attribute__((ext_vector_type(4)));

#define MFMA16(A, B, C) __builtin_amdgcn_mfma_f32_16x16x32_bf16(A, B, C, 0, 0, 0)
#define NEG_BIG -30000.0f

// async 16B global->LDS: lds dest = wave-uniform base + lane*16
#define GLOAD_LDS16(gptr, lptr)                                                \
    __builtin_amdgcn_global_load_lds(                                          \
        (__attribute__((address_space(1))) void*)(gptr),                       \
        (__attribute__((address_space(3))) void*)(lptr), 16, 0, 0)

// XOR swizzle for 64-elem bf16 rows (chunk = 8 elems = 16B)
#define SW(r, c8) ((r) * 64 + (((((c8) >> 3) ^ ((r) & 7))) << 3))

// ---------------------------------------------------------------------------
__global__ void mark_k(float* __restrict__ out, float val, int n) {
    int i = blockIdx.x * 256 + threadIdx.x;
    if (i < n) out[i] = val;
}

// ---------------------------------------------------------------------------
__global__ __launch_bounds__(256) void cvt_x_k(const float* __restrict__ src,
                                               bf16* __restrict__ dst, int n) {
    int i = (blockIdx.x * 256 + threadIdx.x) * 8;
    if (i >= n) return;
    float4 a = *(const float4*)&src[i];
    float4 b = *(const float4*)&src[i + 4];
    bf16x8 w;
    w[0] = (bf16)a.x; w[1] = (bf16)a.y; w[2] = (bf16)a.z; w[3] = (bf16)a.w;
    w[4] = (bf16)b.x; w[5] = (bf16)b.y; w[6] = (bf16)b.z; w[7] = (bf16)b.w;
    *(bf16x8*)&dst[i] = w;
}

// ---------------------------------------------------------------------------
__global__ __launch_bounds__(256) void transpose_cvt_tiled(
    const float* __restrict__ src, bf16* __restrict__ dst, int R, int C) {
    __shared__ float t[32][33];
    int tid = threadIdx.x, tx = tid & 31, ty = tid >> 5;
    int bx = blockIdx.x * 32, by = blockIdx.y * 32;
#pragma unroll
    for (int i = 0; i < 4; ++i) {
        int row = by + ty + i * 8;
        t[ty + i * 8][tx] = src[(size_t)row * C + bx + tx];
    }
    __syncthreads();
#pragma unroll
    for (int i = 0; i < 4; ++i) {
        int outrow = bx + ty + i * 8;
        dst[(size_t)outrow * R + by + tx] = (bf16)t[tx][ty + i * 8];
    }
}

// ---------------------------------------------------------------------------
// QKV GEMM v3 (R15 structure): BK=64, swizzled async staging, transposed D,
// packed Q/K epilogue. Q pre-scaled by 0.125 (natural-exp domain).
// ---------------------------------------------------------------------------
__global__ __launch_bounds__(256) void gemm_qkv_v3(
    const bf16* __restrict__ A, const bf16* __restrict__ B,
    const float* __restrict__ bias, bf16* __restrict__ Qh,
    bf16* __restrict__ Kh, bf16* __restrict__ Vth) {
    __shared__ __align__(16) bf16 As[128 * 64];
    __shared__ __align__(16) bf16 Bs[128 * 64];
    int tid = threadIdx.x, lane = tid & 63, wave = tid >> 6;
    int quad = lane >> 4, l16 = lane & 15;
    int wr = wave >> 1, wc = wave & 1;
    int m0 = blockIdx.y * 128, n0 = blockIdx.x * 128;
    const int K = 768;
    const f32x4 fz = {0.f, 0.f, 0.f, 0.f};
    f32x4 acc[4][4];   // [nj][mi], transposed D
#pragma unroll
    for (int nj = 0; nj < 4; ++nj)
#pragma unroll
        for (int mi = 0; mi < 4; ++mi) acc[nj][mi] = fz;
    const bf16* Ablk = A + (size_t)m0 * K;
    const bf16* Bblk = B + (size_t)n0 * K;
    int lrow8 = lane >> 3;
    int sc = ((lane & 7) ^ (lrow8 & 7)) << 3;

    for (int k0 = 0; k0 < K; k0 += 64) {
        __syncthreads();
#pragma unroll
        for (int i = 0; i < 4; ++i) {
            int r0 = i * 32 + wave * 8;
            int row = r0 + lrow8;
            GLOAD_LDS16(&Ablk[(size_t)row * K + k0 + sc], &As[r0 * 64]);
            GLOAD_LDS16(&Bblk[(size_t)row * K + k0 + sc], &Bs[r0 * 64]);
        }
        __syncthreads();
        bf16x8 af[2][4], bfv[2][4];
#pragma unroll
        for (int t = 0; t < 4; ++t)
#pragma unroll
            for (int hh = 0; hh < 2; ++hh) {
                af[hh][t]  = *(const bf16x8*)&As[SW(wr * 64 + t * 16 + l16, hh * 32 + quad * 8)];
                bfv[hh][t] = *(const bf16x8*)&Bs[SW(wc * 64 + t * 16 + l16, hh * 32 + quad * 8)];
            }
#pragma unroll
        for (int nj = 0; nj < 4; ++nj)
#pragma unroll
            for (int mi = 0; mi < 4; ++mi) {
                acc[nj][mi] = MFMA16(bfv[0][nj], af[0][mi], acc[nj][mi]);
                acc[nj][mi] = MFMA16(bfv[1][nj], af[1][mi], acc[nj][mi]);
            }
    }

#pragma unroll
    for (int nj = 0; nj < 4; ++nj) {
        int c0 = n0 + wc * 64 + nj * 16 + quad * 4;
        float4 bv4 = *(const float4*)&bias[c0];
        float bv[4] = {bv4.x, bv4.y, bv4.z, bv4.w};
        int which = c0 / 768, rr = c0 % 768;
        int h = rr >> 6, d0 = rr & 63;
#pragma unroll
        for (int mi = 0; mi < 4; ++mi) {
            int xrow = m0 + wr * 64 + mi * 16 + l16;
            int b = xrow >> 11, l = xrow & 2047;
            size_t bh = (size_t)(b * 12 + h);
            if (which == 0) {
                bf16x4 v;
#pragma unroll
                for (int r = 0; r < 4; ++r)
                    v[r] = (bf16)((acc[nj][mi][r] + bv[r]) * 0.125f);
                *(bf16x4*)&Qh[(bh * 2048 + l) * 64 + d0] = v;
            } else if (which == 1) {
                bf16x4 v;
#pragma unroll
                for (int r = 0; r < 4; ++r) v[r] = (bf16)(acc[nj][mi][r] + bv[r]);
                *(bf16x4*)&Kh[(bh * 2048 + l) * 64 + d0] = v;
            } else {
#pragma unroll
                for (int r = 0; r < 4; ++r)
                    Vth[(bh * 64 + d0 + r) * 2048 + l] = (bf16)(acc[nj][mi][r] + bv[r]);
            }
        }
    }
}

// ---------------------------------------------------------------------------
// Out-projection GEMM v3 (unchanged): 128M x 64N, 128 thr, grid (12,32).
// ---------------------------------------------------------------------------
__global__ __launch_bounds__(128) void gemm_out_v3(
    const bf16* __restrict__ A, const bf16* __restrict__ B,
    const float* __restrict__ bias, float* __restrict__ C) {
    __shared__ __align__(16) bf16 As[128 * 32];
    __shared__ __align__(16) bf16 Bs[64 * 32];
    int tid = threadIdx.x, lane = tid & 63, wave = tid >> 6;
    int quad = lane >> 4, l16 = lane & 15;
    int m0 = blockIdx.y * 128, n0 = blockIdx.x * 64;
    const int K = 768, N = 768;
    const f32x4 fz = {0.f, 0.f, 0.f, 0.f};
    f32x4 acc[4][4];
#pragma unroll
    for (int mi = 0; mi < 4; ++mi)
#pragma unroll
        for (int nj = 0; nj < 4; ++nj) acc[mi][nj] = fz;
    const bf16* Ablk = A + (size_t)m0 * K;
    const bf16* Bblk = B + (size_t)n0 * K;
    int grow = tid >> 2, gcol = (tid & 3) * 8;

    for (int k0 = 0; k0 < K; k0 += 32) {
        __syncthreads();
#pragma unroll
        for (int i = 0; i < 4; ++i)
            GLOAD_LDS16(&Ablk[(size_t)(i * 32 + grow) * K + k0 + gcol],
                        &As[i * 1024 + wave * 512]);
#pragma unroll
        for (int i = 0; i < 2; ++i)
            GLOAD_LDS16(&Bblk[(size_t)(i * 32 + grow) * K + k0 + gcol],
                        &Bs[i * 1024 + wave * 512]);
        __syncthreads();
        bf16x8 af[4], bfv[4];
#pragma unroll
        for (int t = 0; t < 4; ++t) {
            af[t]  = *(const bf16x8*)&As[(wave * 64 + t * 16 + l16) * 32 + quad * 8];
            bfv[t] = *(const bf16x8*)&Bs[(t * 16 + l16) * 32 + quad * 8];
        }
#pragma unroll
        for (int mi = 0; mi < 4; ++mi)
#pragma unroll
            for (int nj = 0; nj < 4; ++nj)
                acc[mi][nj] = MFMA16(af[mi], bfv[nj], acc[mi][nj]);
    }

#pragma unroll
    for (int nj = 0; nj < 4; ++nj) {
        int col = n0 + nj * 16 + l16;
        float bv = bias[col];
#pragma unroll
        for (int mi = 0; mi < 4; ++mi)
#pragma unroll
            for (int r = 0; r < 4; ++r) {
                int row = m0 + wave * 64 + mi * 16 + quad * 4 + r;
                C[(size_t)row * N + col] = acc[mi][nj][r] + bv;
            }
    }
}

// ---------------------------------------------------------------------------
// Flash attention v6: 256 threads / 4 waves, block covers 128 qrows (each
// wave 32 qrows as 2 qtiles). Grid (16, 24) = 384 blocks -> wall = 2 rounds
// (was 3 at 768 blocks). K/V staging cooperative across 4 waves (per-thread
// cost halves). Clean-mask fast path skips mask adds (uniform branch).
// __expf domain (native v_exp), Q pre-scaled 0.125. Proven v3 per-wave body.
// ---------------------------------------------------------------------------
#define PLD 72

__global__ __launch_bounds__(256) void flash_attn(
    const bf16* __restrict__ Q, const bf16* __restrict__ K,
    const bf16* __restrict__ V, const int* __restrict__ mask,
    bf16* __restrict__ ctx) {
    __shared__ __align__(16) bf16 Ks[2][64 * 64];
    __shared__ __align__(16) bf16 Vs[2][64 * 64];
    __shared__ __align__(16) bf16 Ps[4][16 * PLD];
    __shared__ float maskS[2048];
    __shared__ int cleanF;

    int tid = threadIdx.x, lane = tid & 63, wave = tid >> 6;  // wave 0..3
    int quad = lane >> 4, l16 = lane & 15;
    int bh = blockIdx.y, b = bh / 12;
    int q0 = blockIdx.x * 128 + wave * 32;

    bf16x8 aq[2][2];
#pragma unroll
    for (int qt = 0; qt < 2; ++qt) {
        const bf16* Qp = Q + ((size_t)bh * 2048 + q0 + qt * 16 + l16) * 64;
        aq[qt][0] = *(const bf16x8*)(Qp + quad * 8);
        aq[qt][1] = *(const bf16x8*)(Qp + 32 + quad * 8);
    }

    if (tid == 0) cleanF = 1;
    __syncthreads();
    const int* mrow = mask + b * 2048;
    int myclean = 1;
#pragma unroll
    for (int i = 0; i < 8; ++i) {
        int idx = i * 256 + tid;
        int mv = mrow[idx];
        maskS[idx] = mv ? 0.0f : NEG_BIG;
        myclean &= (mv != 0);
    }
    if (!myclean) cleanF = 0;   // benign race: all writers store 0

    const f32x4 fz = {0.f, 0.f, 0.f, 0.f};
    f32x4 o[2][4];
    float m_i[2], l_i[2];
#pragma unroll
    for (int qt = 0; qt < 2; ++qt) {
        m_i[qt] = NEG_BIG; l_i[qt] = 0.f;
#pragma unroll
        for (int dt = 0; dt < 4; ++dt) o[qt][dt] = fz;
    }

    // Cooperative staging: 256 threads cover 64 rows x 8 chunks x2 (K,V)
    int srow = tid >> 3;            // 0..31 (two row-halves below)
    int sc8  = (tid & 7) * 8;
    const bf16* Kbase = K + (size_t)bh * 2048 * 64;
    const bf16* Vbase = V + (size_t)bh * 64 * 2048;

#pragma unroll
    for (int i = 0; i < 2; ++i) {
        int row = srow + i * 32;
        *(bf16x8*)&Ks[0][SW(row, sc8)] =
            *(const bf16x8*)&Kbase[(size_t)row * 64 + sc8];
        *(bf16x8*)&Vs[0][SW(row, sc8)] =
            *(const bf16x8*)&Vbase[(size_t)row * 2048 + sc8];
    }
    __syncthreads();
    int clean = cleanF;   // uniform

    int p = 0;
    for (int kb = 0; kb < 2048; kb += 64) {
        __syncthreads();

        if (kb + 64 < 2048) {
            int nb = kb + 64;
#pragma unroll
            for (int i = 0; i < 2; ++i) {
                int row = srow + i * 32;
                *(bf16x8*)&Ks[1 - p][SW(row, sc8)] =
                    *(const bf16x8*)&Kbase[(size_t)(nb + row) * 64 + sc8];
                *(bf16x8*)&Vs[1 - p][SW(row, sc8)] =
                    *(const bf16x8*)&Vbase[(size_t)row * 2048 + nb + sc8];
            }
        }

        // S^T = K Q^T : key = ct*16 + quad*4 + r, qrow = l16
        f32x4 s[2][4];
#pragma unroll
        for (int ct = 0; ct < 4; ++ct) {
            int krow = ct * 16 + l16;
            bf16x8 kf0 = *(const bf16x8*)&Ks[p][SW(krow, quad * 8)];
            bf16x8 kf1 = *(const bf16x8*)&Ks[p][SW(krow, 32 + quad * 8)];
#pragma unroll
            for (int qt = 0; qt < 2; ++qt) {
                f32x4 t = fz;
                t = MFMA16(kf0, aq[qt][0], t);
                t = MFMA16(kf1, aq[qt][1], t);
                s[qt][ct] = t;
            }
        }

        if (!clean) {
#pragma unroll
            for (int ct = 0; ct < 4; ++ct) {
                const float* mk = &maskS[kb + ct * 16 + quad * 4];
                float4 mv = *(const float4*)mk;
                float ma[4] = {mv.x, mv.y, mv.z, mv.w};
#pragma unroll
                for (int qt = 0; qt < 2; ++qt)
#pragma unroll
                    for (int r = 0; r < 4; ++r) s[qt][ct][r] += ma[r];
            }
        }

        float alpha[2];
#pragma unroll
        for (int qt = 0; qt < 2; ++qt) {
            float mx = NEG_BIG;
#pragma unroll
            for (int ct = 0; ct < 4; ++ct)
#pragma unroll
                for (int r = 0; r < 4; ++r) mx = fmaxf(mx, s[qt][ct][r]);
            mx = fmaxf(mx, __shfl_xor(mx, 16));
            mx = fmaxf(mx, __shfl_xor(mx, 32));
            float nm = fmaxf(m_i[qt], mx);
            alpha[qt] = __expf(m_i[qt] - nm);
            m_i[qt] = nm;
            float sum = 0.f;
#pragma unroll
            for (int ct = 0; ct < 4; ++ct)
#pragma unroll
                for (int r = 0; r < 4; ++r) {
                    float pv = __expf(s[qt][ct][r] - nm);
                    s[qt][ct][r] = pv;
                    sum += pv;
                }
            sum += __shfl_xor(sum, 16);
            sum += __shfl_xor(sum, 32);
            l_i[qt] = l_i[qt] * alpha[qt] + sum;
        }

#pragma unroll
        for (int qt = 0; qt < 2; ++qt) {
            float ab[4];
#pragma unroll
            for (int r = 0; r < 4; ++r)
                ab[r] = __shfl(alpha[qt], (lane & 48) | (quad * 4 + r));
#pragma unroll
            for (int dt = 0; dt < 4; ++dt)
#pragma unroll
                for (int r = 0; r < 4; ++r) o[qt][dt][r] *= ab[r];
        }

        bf16x8 vf[2][4];
#pragma unroll
        for (int ks = 0; ks < 2; ++ks)
#pragma unroll
            for (int dt = 0; dt < 4; ++dt)
                vf[ks][dt] = *(const bf16x8*)&Vs[p][SW(dt * 16 + l16, ks * 32 + quad * 8)];

#pragma unroll
        for (int qt = 0; qt < 2; ++qt) {
#pragma unroll
            for (int ct = 0; ct < 4; ++ct) {
                bf16x4 pk;
#pragma unroll
                for (int r = 0; r < 4; ++r) pk[r] = (bf16)s[qt][ct][r];
                *(bf16x4*)&Ps[wave][l16 * PLD + ct * 16 + quad * 4] = pk;
            }
#pragma unroll
            for (int ks = 0; ks < 2; ++ks) {
                bf16x8 ap = *(const bf16x8*)&Ps[wave][l16 * PLD + ks * 32 + quad * 8];
#pragma unroll
                for (int dt = 0; dt < 4; ++dt)
                    o[qt][dt] = MFMA16(ap, vf[ks][dt], o[qt][dt]);
            }
        }
        p ^= 1;
    }

    int h = bh % 12;
#pragma unroll
    for (int qt = 0; qt < 2; ++qt) {
        float linv[4];
#pragma unroll
        for (int r = 0; r < 4; ++r)
            linv[r] = 1.0f / __shfl(l_i[qt], (lane & 48) | (quad * 4 + r));
#pragma unroll
        for (int dt = 0; dt < 4; ++dt)
#pragma unroll
            for (int r = 0; r < 4; ++r) {
                int qrow = q0 + qt * 16 + quad * 4 + r;
                ctx[((size_t)b * 2048 + qrow) * 768 + h * 64 + dt * 16 + l16] =
                    (bf16)(o[qt][dt][r] * linv[r]);
            }
    }
}

// ---------------------------------------------------------------------------
extern "C" void kernel_launch(void* const* d_in, const int* in_sizes, int n_in,
                              void* d_out, int out_size, void* d_ws, size_t ws_size,
                              hipStream_t stream) {
    float* out = (float*)d_out;

    const float* x = nullptr; const int* mask = nullptr;
    const float* w_qkv = nullptr; const float* b_qkv = nullptr;
    const float* w_out = nullptr; const float* b_out = nullptr;
    int found = 0;
    for (int i = 0; i < n_in; ++i) {
        switch (in_sizes[i]) {
            case 3145728: x     = (const float*)d_in[i]; found |= 1;  break;
            case 4096:    mask  = (const int*)  d_in[i]; found |= 2;  break;
            case 1769472: w_qkv = (const float*)d_in[i]; found |= 4;  break;
            case 2304:    b_qkv = (const float*)d_in[i]; found |= 8;  break;
            case 589824:  w_out = (const float*)d_in[i]; found |= 16; break;
            case 768:     b_out = (const float*)d_in[i]; found |= 32; break;
        }
    }
    if (found != 63) {
        mark_k<<<(out_size + 255) / 256, 256, 0, stream>>>(
            out, 200.0f + (float)found, out_size);
        return;
    }

    const int M = 4096, D = 768, N3 = 2304;
    const size_t HEADS_ELEMS = (size_t)24 * 2048 * 64;

    bf16* ws    = (bf16*)d_ws;
    bf16* Kh    = ws;
    bf16* Vth   = Kh + HEADS_ELEMS;
    bf16* ctx   = Vth + HEADS_ELEMS;
    bf16* wqkvT = ctx + (size_t)M * D;
    bf16* woutT = wqkvT + (size_t)N3 * D;
    bf16* Qh    = (bf16*)d_out;
    bf16* xb    = (bf16*)d_out + HEADS_ELEMS;

    cvt_x_k<<<(M * D / 8 + 255) / 256, 256, 0, stream>>>(x, xb, M * D);
    transpose_cvt_tiled<<<dim3(2304 / 32, 768 / 32), 256, 0, stream>>>(
        w_qkv, wqkvT, 768, 2304);
    transpose_cvt_tiled<<<dim3(768 / 32, 768 / 32), 256, 0, stream>>>(
        w_out, woutT, 768, 768);

    gemm_qkv_v3<<<dim3(N3 / 128, M / 128), 256, 0, stream>>>(
        xb, wqkvT, b_qkv, Qh, Kh, Vth);

    flash_attn<<<dim3(2048 / 128, 24), 256, 0, stream>>>(Qh, Kh, Vth, mask, ctx);

    gemm_out_v3<<<dim3(D / 64, M / 128), 128, 0, stream>>>(
        ctx, woutT, b_out, out);
}

// Round 17
// 202.055 us; speedup vs baseline: 1.1107x; 1.0298x over previous
//
#include <hip/hip_runtime.h>

typedef __bf16 bf16;
typedef bf16 bf16x4 __attribute__((ext_vector_type(4)));
typedef bf16 bf16x8 __attribute__((ext_vector_type(8)));
typedef float f32x4 __attribute__((ext_vector_type(4)));

#define MFMA16(A, B, C) __builtin_amdgcn_mfma_f32_16x16x32_bf16(A, B, C, 0, 0, 0)
#define NEG_BIG -30000.0f

// async 16B global->LDS: lds dest = wave-uniform base + lane*16
#define GLOAD_LDS16(gptr, lptr)                                                \
    __builtin_amdgcn_global_load_lds(                                          \
        (__attribute__((address_space(1))) void*)(gptr),                       \
        (__attribute__((address_space(3))) void*)(lptr), 16, 0, 0)

// XOR swizzle for 64-elem bf16 rows (chunk = 8 elems = 16B)
#define SW(r, c8) ((r) * 64 + (((((c8) >> 3) ^ ((r) & 7))) << 3))

// ---------------------------------------------------------------------------
__global__ void mark_k(float* __restrict__ out, float val, int n) {
    int i = blockIdx.x * 256 + threadIdx.x;
    if (i < n) out[i] = val;
}

// ---------------------------------------------------------------------------
__global__ __launch_bounds__(256) void cvt_x_k(const float* __restrict__ src,
                                               bf16* __restrict__ dst, int n) {
    int i = (blockIdx.x * 256 + threadIdx.x) * 8;
    if (i >= n) return;
    float4 a = *(const float4*)&src[i];
    float4 b = *(const float4*)&src[i + 4];
    bf16x8 w;
    w[0] = (bf16)a.x; w[1] = (bf16)a.y; w[2] = (bf16)a.z; w[3] = (bf16)a.w;
    w[4] = (bf16)b.x; w[5] = (bf16)b.y; w[6] = (bf16)b.z; w[7] = (bf16)b.w;
    *(bf16x8*)&dst[i] = w;
}

// ---------------------------------------------------------------------------
__global__ __launch_bounds__(256) void transpose_cvt_tiled(
    const float* __restrict__ src, bf16* __restrict__ dst, int R, int C) {
    __shared__ float t[32][33];
    int tid = threadIdx.x, tx = tid & 31, ty = tid >> 5;
    int bx = blockIdx.x * 32, by = blockIdx.y * 32;
#pragma unroll
    for (int i = 0; i < 4; ++i) {
        int row = by + ty + i * 8;
        t[ty + i * 8][tx] = src[(size_t)row * C + bx + tx];
    }
    __syncthreads();
#pragma unroll
    for (int i = 0; i < 4; ++i) {
        int outrow = bx + ty + i * 8;
        dst[(size_t)outrow * R + by + tx] = (bf16)t[tx][ty + i * 8];
    }
}

// ---------------------------------------------------------------------------
// QKV GEMM v4: R15 inner loop (BK=64, swizzled async staging, transposed D)
// + LDS-staged COALESCED epilogue. Each block's 128-col range lies in exactly
// one of Q/K/V (768/128=6 blocks per third) and spans 2 heads. Output tile is
// staged in LDS (V-third transposed during staging), then streamed out with
// 16B coalesced stores. Q pre-scaled by 0.125.
// ---------------------------------------------------------------------------
#define CLD 136   // epilogue LDS leading dim: 272B rows (16B-aligned)

__global__ __launch_bounds__(256) void gemm_qkv_v4(
    const bf16* __restrict__ A, const bf16* __restrict__ B,
    const float* __restrict__ bias, bf16* __restrict__ Qh,
    bf16* __restrict__ Kh, bf16* __restrict__ Vth) {
    __shared__ __align__(16) bf16 SMEM[128 * CLD];   // 34816 B; staging + epi
    bf16* As = SMEM;            // 128*64
    bf16* Bs = SMEM + 8192;     // 128*64

    int tid = threadIdx.x, lane = tid & 63, wave = tid >> 6;
    int quad = lane >> 4, l16 = lane & 15;
    int wr = wave >> 1, wc = wave & 1;
    int m0 = blockIdx.y * 128, n0 = blockIdx.x * 128;
    const int K = 768;
    const f32x4 fz = {0.f, 0.f, 0.f, 0.f};
    f32x4 acc[4][4];   // [nj][mi], transposed D
#pragma unroll
    for (int nj = 0; nj < 4; ++nj)
#pragma unroll
        for (int mi = 0; mi < 4; ++mi) acc[nj][mi] = fz;
    const bf16* Ablk = A + (size_t)m0 * K;
    const bf16* Bblk = B + (size_t)n0 * K;
    int lrow8 = lane >> 3;
    int sc = ((lane & 7) ^ (lrow8 & 7)) << 3;

    for (int k0 = 0; k0 < K; k0 += 64) {
        __syncthreads();
#pragma unroll
        for (int i = 0; i < 4; ++i) {
            int r0 = i * 32 + wave * 8;
            int row = r0 + lrow8;
            GLOAD_LDS16(&Ablk[(size_t)row * K + k0 + sc], &As[r0 * 64]);
            GLOAD_LDS16(&Bblk[(size_t)row * K + k0 + sc], &Bs[r0 * 64]);
        }
        __syncthreads();
        bf16x8 af[2][4], bfv[2][4];
#pragma unroll
        for (int t = 0; t < 4; ++t)
#pragma unroll
            for (int hh = 0; hh < 2; ++hh) {
                af[hh][t]  = *(const bf16x8*)&As[SW(wr * 64 + t * 16 + l16, hh * 32 + quad * 8)];
                bfv[hh][t] = *(const bf16x8*)&Bs[SW(wc * 64 + t * 16 + l16, hh * 32 + quad * 8)];
            }
#pragma unroll
        for (int nj = 0; nj < 4; ++nj)
#pragma unroll
            for (int mi = 0; mi < 4; ++mi) {
                acc[nj][mi] = MFMA16(bfv[0][nj], af[0][mi], acc[nj][mi]);
                acc[nj][mi] = MFMA16(bfv[1][nj], af[1][mi], acc[nj][mi]);
            }
    }

    // ---- Epilogue: acc -> LDS tile -> coalesced global stores ----
    int which = n0 / 768;                 // uniform per block
    int h0 = (n0 % 768) >> 6;             // first of 2 heads in this block
    int b = m0 >> 11, l0 = m0 & 2047;
    __syncthreads();   // staging buffers dead

    if (which == 2) {
        // store TRANSPOSED into LDS: Cs[col_local][xrow_local]
#pragma unroll
        for (int nj = 0; nj < 4; ++nj) {
            int cl0 = wc * 64 + nj * 16 + quad * 4;
            float4 bv4 = *(const float4*)&bias[n0 + cl0];
            float bv[4] = {bv4.x, bv4.y, bv4.z, bv4.w};
#pragma unroll
            for (int mi = 0; mi < 4; ++mi) {
                int xrl = wr * 64 + mi * 16 + l16;
#pragma unroll
                for (int r = 0; r < 4; ++r)
                    SMEM[(cl0 + r) * CLD + xrl] = (bf16)(acc[nj][mi][r] + bv[r]);
            }
        }
    } else {
        float s = (which == 0) ? 0.125f : 1.0f;
#pragma unroll
        for (int nj = 0; nj < 4; ++nj) {
            int cl0 = wc * 64 + nj * 16 + quad * 4;
            float4 bv4 = *(const float4*)&bias[n0 + cl0];
            float bv[4] = {bv4.x, bv4.y, bv4.z, bv4.w};
#pragma unroll
            for (int mi = 0; mi < 4; ++mi) {
                int xrl = wr * 64 + mi * 16 + l16;
                bf16x4 v;
#pragma unroll
                for (int r = 0; r < 4; ++r) v[r] = (bf16)((acc[nj][mi][r] + bv[r]) * s);
                *(bf16x4*)&SMEM[xrl * CLD + cl0] = v;
            }
        }
    }
    __syncthreads();

    // coalesced read-out: 2048 chunks of 16B, 8 per thread
    if (which == 2) {
#pragma unroll
        for (int i = 0; i < 8; ++i) {
            int idx = i * 256 + tid;
            int cl = idx >> 4, ch = idx & 15;       // cl = col_local (d), ch = l chunk
            int d = cl & 63, h = h0 + (cl >> 6);
            bf16x8 v = *(const bf16x8*)&SMEM[cl * CLD + ch * 8];
            *(bf16x8*)&Vth[((size_t)(b * 12 + h) * 64 + d) * 2048 + l0 + ch * 8] = v;
        }
    } else {
        bf16* dst = (which == 0) ? Qh : Kh;
#pragma unroll
        for (int i = 0; i < 8; ++i) {
            int idx = i * 256 + tid;
            int rr = idx >> 4, ch = idx & 15;       // rr = xrow_local
            int h = h0 + (ch >> 3), d0 = (ch & 7) * 8;
            bf16x8 v = *(const bf16x8*)&SMEM[rr * CLD + ch * 8];
            *(bf16x8*)&dst[((size_t)(b * 12 + h) * 2048 + l0 + rr) * 64 + d0] = v;
        }
    }
}

// ---------------------------------------------------------------------------
// Out-projection GEMM v3 (unchanged): 128M x 64N, 128 thr, grid (12,32).
// C-layout stores are already coalesced (col = l16, 4B consecutive).
// ---------------------------------------------------------------------------
__global__ __launch_bounds__(128) void gemm_out_v3(
    const bf16* __restrict__ A, const bf16* __restrict__ B,
    const float* __restrict__ bias, float* __restrict__ C) {
    __shared__ __align__(16) bf16 As[128 * 32];
    __shared__ __align__(16) bf16 Bs[64 * 32];
    int tid = threadIdx.x, lane = tid & 63, wave = tid >> 6;
    int quad = lane >> 4, l16 = lane & 15;
    int m0 = blockIdx.y * 128, n0 = blockIdx.x * 64;
    const int K = 768, N = 768;
    const f32x4 fz = {0.f, 0.f, 0.f, 0.f};
    f32x4 acc[4][4];
#pragma unroll
    for (int mi = 0; mi < 4; ++mi)
#pragma unroll
        for (int nj = 0; nj < 4; ++nj) acc[mi][nj] = fz;
    const bf16* Ablk = A + (size_t)m0 * K;
    const bf16* Bblk = B + (size_t)n0 * K;
    int grow = tid >> 2, gcol = (tid & 3) * 8;

    for (int k0 = 0; k0 < K; k0 += 32) {
        __syncthreads();
#pragma unroll
        for (int i = 0; i < 4; ++i)
            GLOAD_LDS16(&Ablk[(size_t)(i * 32 + grow) * K + k0 + gcol],
                        &As[i * 1024 + wave * 512]);
#pragma unroll
        for (int i = 0; i < 2; ++i)
            GLOAD_LDS16(&Bblk[(size_t)(i * 32 + grow) * K + k0 + gcol],
                        &Bs[i * 1024 + wave * 512]);
        __syncthreads();
        bf16x8 af[4], bfv[4];
#pragma unroll
        for (int t = 0; t < 4; ++t) {
            af[t]  = *(const bf16x8*)&As[(wave * 64 + t * 16 + l16) * 32 + quad * 8];
            bfv[t] = *(const bf16x8*)&Bs[(t * 16 + l16) * 32 + quad * 8];
        }
#pragma unroll
        for (int mi = 0; mi < 4; ++mi)
#pragma unroll
            for (int nj = 0; nj < 4; ++nj)
                acc[mi][nj] = MFMA16(af[mi], bfv[nj], acc[mi][nj]);
    }

#pragma unroll
    for (int nj = 0; nj < 4; ++nj) {
        int col = n0 + nj * 16 + l16;
        float bv = bias[col];
#pragma unroll
        for (int mi = 0; mi < 4; ++mi)
#pragma unroll
            for (int r = 0; r < 4; ++r) {
                int row = m0 + wave * 64 + mi * 16 + quad * 4 + r;
                C[(size_t)row * N + col] = acc[mi][nj][r] + bv;
            }
    }
}

// ---------------------------------------------------------------------------
// Flash attention v6 (unchanged from R16: 84.5 us).
// ---------------------------------------------------------------------------
#define PLD 72

__global__ __launch_bounds__(256) void flash_attn(
    const bf16* __restrict__ Q, const bf16* __restrict__ K,
    const bf16* __restrict__ V, const int* __restrict__ mask,
    bf16* __restrict__ ctx) {
    __shared__ __align__(16) bf16 Ks[2][64 * 64];
    __shared__ __align__(16) bf16 Vs[2][64 * 64];
    __shared__ __align__(16) bf16 Ps[4][16 * PLD];
    __shared__ float maskS[2048];
    __shared__ int cleanF;

    int tid = threadIdx.x, lane = tid & 63, wave = tid >> 6;
    int quad = lane >> 4, l16 = lane & 15;
    int bh = blockIdx.y, b = bh / 12;
    int q0 = blockIdx.x * 128 + wave * 32;

    bf16x8 aq[2][2];
#pragma unroll
    for (int qt = 0; qt < 2; ++qt) {
        const bf16* Qp = Q + ((size_t)bh * 2048 + q0 + qt * 16 + l16) * 64;
        aq[qt][0] = *(const bf16x8*)(Qp + quad * 8);
        aq[qt][1] = *(const bf16x8*)(Qp + 32 + quad * 8);
    }

    if (tid == 0) cleanF = 1;
    __syncthreads();
    const int* mrow = mask + b * 2048;
    int myclean = 1;
#pragma unroll
    for (int i = 0; i < 8; ++i) {
        int idx = i * 256 + tid;
        int mv = mrow[idx];
        maskS[idx] = mv ? 0.0f : NEG_BIG;
        myclean &= (mv != 0);
    }
    if (!myclean) cleanF = 0;

    const f32x4 fz = {0.f, 0.f, 0.f, 0.f};
    f32x4 o[2][4];
    float m_i[2], l_i[2];
#pragma unroll
    for (int qt = 0; qt < 2; ++qt) {
        m_i[qt] = NEG_BIG; l_i[qt] = 0.f;
#pragma unroll
        for (int dt = 0; dt < 4; ++dt) o[qt][dt] = fz;
    }

    int srow = tid >> 3;
    int sc8  = (tid & 7) * 8;
    const bf16* Kbase = K + (size_t)bh * 2048 * 64;
    const bf16* Vbase = V + (size_t)bh * 64 * 2048;

#pragma unroll
    for (int i = 0; i < 2; ++i) {
        int row = srow + i * 32;
        *(bf16x8*)&Ks[0][SW(row, sc8)] =
            *(const bf16x8*)&Kbase[(size_t)row * 64 + sc8];
        *(bf16x8*)&Vs[0][SW(row, sc8)] =
            *(const bf16x8*)&Vbase[(size_t)row * 2048 + sc8];
    }
    __syncthreads();
    int clean = cleanF;

    int p = 0;
    for (int kb = 0; kb < 2048; kb += 64) {
        __syncthreads();

        if (kb + 64 < 2048) {
            int nb = kb + 64;
#pragma unroll
            for (int i = 0; i < 2; ++i) {
                int row = srow + i * 32;
                *(bf16x8*)&Ks[1 - p][SW(row, sc8)] =
                    *(const bf16x8*)&Kbase[(size_t)(nb + row) * 64 + sc8];
                *(bf16x8*)&Vs[1 - p][SW(row, sc8)] =
                    *(const bf16x8*)&Vbase[(size_t)row * 2048 + nb + sc8];
            }
        }

        f32x4 s[2][4];
#pragma unroll
        for (int ct = 0; ct < 4; ++ct) {
            int krow = ct * 16 + l16;
            bf16x8 kf0 = *(const bf16x8*)&Ks[p][SW(krow, quad * 8)];
            bf16x8 kf1 = *(const bf16x8*)&Ks[p][SW(krow, 32 + quad * 8)];
#pragma unroll
            for (int qt = 0; qt < 2; ++qt) {
                f32x4 t = fz;
                t = MFMA16(kf0, aq[qt][0], t);
                t = MFMA16(kf1, aq[qt][1], t);
                s[qt][ct] = t;
            }
        }

        if (!clean) {
#pragma unroll
            for (int ct = 0; ct < 4; ++ct) {
                const float* mk = &maskS[kb + ct * 16 + quad * 4];
                float4 mv = *(const float4*)mk;
                float ma[4] = {mv.x, mv.y, mv.z, mv.w};
#pragma unroll
                for (int qt = 0; qt < 2; ++qt)
#pragma unroll
                    for (int r = 0; r < 4; ++r) s[qt][ct][r] += ma[r];
            }
        }

        float alpha[2];
#pragma unroll
        for (int qt = 0; qt < 2; ++qt) {
            float mx = NEG_BIG;
#pragma unroll
            for (int ct = 0; ct < 4; ++ct)
#pragma unroll
                for (int r = 0; r < 4; ++r) mx = fmaxf(mx, s[qt][ct][r]);
            mx = fmaxf(mx, __shfl_xor(mx, 16));
            mx = fmaxf(mx, __shfl_xor(mx, 32));
            float nm = fmaxf(m_i[qt], mx);
            alpha[qt] = __expf(m_i[qt] - nm);
            m_i[qt] = nm;
            float sum = 0.f;
#pragma unroll
            for (int ct = 0; ct < 4; ++ct)
#pragma unroll
                for (int r = 0; r < 4; ++r) {
                    float pv = __expf(s[qt][ct][r] - nm);
                    s[qt][ct][r] = pv;
                    sum += pv;
                }
            sum += __shfl_xor(sum, 16);
            sum += __shfl_xor(sum, 32);
            l_i[qt] = l_i[qt] * alpha[qt] + sum;
        }

#pragma unroll
        for (int qt = 0; qt < 2; ++qt) {
            float ab[4];
#pragma unroll
            for (int r = 0; r < 4; ++r)
                ab[r] = __shfl(alpha[qt], (lane & 48) | (quad * 4 + r));
#pragma unroll
            for (int dt = 0; dt < 4; ++dt)
#pragma unroll
                for (int r = 0; r < 4; ++r) o[qt][dt][r] *= ab[r];
        }

        bf16x8 vf[2][4];
#pragma unroll
        for (int ks = 0; ks < 2; ++ks)
#pragma unroll
            for (int dt = 0; dt < 4; ++dt)
                vf[ks][dt] = *(const bf16x8*)&Vs[p][SW(dt * 16 + l16, ks * 32 + quad * 8)];

#pragma unroll
        for (int qt = 0; qt < 2; ++qt) {
#pragma unroll
            for (int ct = 0; ct < 4; ++ct) {
                bf16x4 pk;
#pragma unroll
                for (int r = 0; r < 4; ++r) pk[r] = (bf16)s[qt][ct][r];
                *(bf16x4*)&Ps[wave][l16 * PLD + ct * 16 + quad * 4] = pk;
            }
#pragma unroll
            for (int ks = 0; ks < 2; ++ks) {
                bf16x8 ap = *(const bf16x8*)&Ps[wave][l16 * PLD + ks * 32 + quad * 8];
#pragma unroll
                for (int dt = 0; dt < 4; ++dt)
                    o[qt][dt] = MFMA16(ap, vf[ks][dt], o[qt][dt]);
            }
        }
        p ^= 1;
    }

    int h = bh % 12;
#pragma unroll
    for (int qt = 0; qt < 2; ++qt) {
        float linv[4];
#pragma unroll
        for (int r = 0; r < 4; ++r)
            linv[r] = 1.0f / __shfl(l_i[qt], (lane & 48) | (quad * 4 + r));
#pragma unroll
        for (int dt = 0; dt < 4; ++dt)
#pragma unroll
            for (int r = 0; r < 4; ++r) {
                int qrow = q0 + qt * 16 + quad * 4 + r;
                ctx[((size_t)b * 2048 + qrow) * 768 + h * 64 + dt * 16 + l16] =
                    (bf16)(o[qt][dt][r] * linv[r]);
            }
    }
}

// ---------------------------------------------------------------------------
extern "C" void kernel_launch(void* const* d_in, const int* in_sizes, int n_in,
                              void* d_out, int out_size, void* d_ws, size_t ws_size,
                              hipStream_t stream) {
    float* out = (float*)d_out;

    const float* x = nullptr; const int* mask = nullptr;
    const float* w_qkv = nullptr; const float* b_qkv = nullptr;
    const float* w_out = nullptr; const float* b_out = nullptr;
    int found = 0;
    for (int i = 0; i < n_in; ++i) {
        switch (in_sizes[i]) {
            case 3145728: x     = (const float*)d_in[i]; found |= 1;  break;
            case 4096:    mask  = (const int*)  d_in[i]; found |= 2;  break;
            case 1769472: w_qkv = (const float*)d_in[i]; found |= 4;  break;
            case 2304:    b_qkv = (const float*)d_in[i]; found |= 8;  break;
            case 589824:  w_out = (const float*)d_in[i]; found |= 16; break;
            case 768:     b_out = (const float*)d_in[i]; found |= 32; break;
        }
    }
    if (found != 63) {
        mark_k<<<(out_size + 255) / 256, 256, 0, stream>>>(
            out, 200.0f + (float)found, out_size);
        return;
    }

    const int M = 4096, D = 768, N3 = 2304;
    const size_t HEADS_ELEMS = (size_t)24 * 2048 * 64;

    bf16* ws    = (bf16*)d_ws;
    bf16* Kh    = ws;
    bf16* Vth   = Kh + HEADS_ELEMS;
    bf16* ctx   = Vth + HEADS_ELEMS;
    bf16* wqkvT = ctx + (size_t)M * D;
    bf16* woutT = wqkvT + (size_t)N3 * D;
    bf16* Qh    = (bf16*)d_out;
    bf16* xb    = (bf16*)d_out + HEADS_ELEMS;

    cvt_x_k<<<(M * D / 8 + 255) / 256, 256, 0, stream>>>(x, xb, M * D);
    transpose_cvt_tiled<<<dim3(2304 / 32, 768 / 32), 256, 0, stream>>>(
        w_qkv, wqkvT, 768, 2304);
    transpose_cvt_tiled<<<dim3(768 / 32, 768 / 32), 256, 0, stream>>>(
        w_out, woutT, 768, 768);

    gemm_qkv_v4<<<dim3(N3 / 128, M / 128), 256, 0, stream>>>(
        xb, wqkvT, b_qkv, Qh, Kh, Vth);

    flash_attn<<<dim3(2048 / 128, 24), 256, 0, stream>>>(Qh, Kh, Vth, mask, ctx);

    gemm_out_v3<<<dim3(D / 64, M / 128), 128, 0, stream>>>(
        ctx, woutT, b_out, out);
}

// Round 18
// 200.610 us; speedup vs baseline: 1.1187x; 1.0072x over previous
//
#include <hip/hip_runtime.h>

typedef __bf16 bf16;
typedef bf16 bf16x4 __attribute__((ext_vector_type(4)));
typedef bf16 bf16x8 __attribute__((ext_vector_type(8)));
typedef float f32x4 __attribute__((ext_vector_type(4)));

#define MFMA16(A, B, C) __builtin_amdgcn_mfma_f32_16x16x32_bf16(A, B, C, 0, 0, 0)
#define NEG_BIG -30000.0f

// async 16B global->LDS: lds dest = wave-uniform base + lane*16
#define GLOAD_LDS16(gptr, lptr)                                                \
    __builtin_amdgcn_global_load_lds(                                          \
        (__attribute__((address_space(1))) void*)(gptr),                       \
        (__attribute__((address_space(3))) void*)(lptr), 16, 0, 0)

// XOR swizzles: 64-elem rows (flash) and 32-elem rows (GEMM BK=32)
#define SW(r, c8) ((r) * 64 + (((((c8) >> 3) ^ ((r) & 7))) << 3))
#define SW32(r, q) ((r) * 32 + ((((q) ^ ((r) & 3))) << 3))

// ---------------------------------------------------------------------------
__global__ void mark_k(float* __restrict__ out, float val, int n) {
    int i = blockIdx.x * 256 + threadIdx.x;
    if (i < n) out[i] = val;
}

// ---------------------------------------------------------------------------
__global__ __launch_bounds__(256) void cvt_x_k(const float* __restrict__ src,
                                               bf16* __restrict__ dst, int n) {
    int i = (blockIdx.x * 256 + threadIdx.x) * 8;
    if (i >= n) return;
    float4 a = *(const float4*)&src[i];
    float4 b = *(const float4*)&src[i + 4];
    bf16x8 w;
    w[0] = (bf16)a.x; w[1] = (bf16)a.y; w[2] = (bf16)a.z; w[3] = (bf16)a.w;
    w[4] = (bf16)b.x; w[5] = (bf16)b.y; w[6] = (bf16)b.z; w[7] = (bf16)b.w;
    *(bf16x8*)&dst[i] = w;
}

// ---------------------------------------------------------------------------
__global__ __launch_bounds__(256) void transpose_cvt_tiled(
    const float* __restrict__ src, bf16* __restrict__ dst, int R, int C) {
    __shared__ float t[32][33];
    int tid = threadIdx.x, tx = tid & 31, ty = tid >> 5;
    int bx = blockIdx.x * 32, by = blockIdx.y * 32;
#pragma unroll
    for (int i = 0; i < 4; ++i) {
        int row = by + ty + i * 8;
        t[ty + i * 8][tx] = src[(size_t)row * C + bx + tx];
    }
    __syncthreads();
#pragma unroll
    for (int i = 0; i < 4; ++i) {
        int outrow = bx + ty + i * 8;
        dst[(size_t)outrow * R + by + tx] = (bf16)t[tx][ty + i * 8];
    }
}

// ---------------------------------------------------------------------------
// QKV GEMM v5: BK=32 DOUBLE-BUFFERED single-barrier K-loop (prefetch next
// k-tile async while computing current), transposed-D MFMA, v4 coalesced
// LDS-staged epilogue. Q pre-scaled by 0.125.
// ---------------------------------------------------------------------------
#define CLD 136   // epilogue LDS leading dim

__global__ __launch_bounds__(256) void gemm_qkv_v5(
    const bf16* __restrict__ A, const bf16* __restrict__ B,
    const float* __restrict__ bias, bf16* __restrict__ Qh,
    bf16* __restrict__ Kh, bf16* __restrict__ Vth) {
    __shared__ __align__(16) bf16 SMEM[128 * CLD];   // 34816 B
    // staging carve (elem offsets): As[p]=p*8192, Bs[p]=4096+p*8192
    int tid = threadIdx.x, lane = tid & 63, wave = tid >> 6;
    int quad = lane >> 4, l16 = lane & 15;
    int wr = wave >> 1, wc = wave & 1;
    int m0 = blockIdx.y * 128, n0 = blockIdx.x * 128;
    const int K = 768;
    const f32x4 fz = {0.f, 0.f, 0.f, 0.f};
    f32x4 acc[4][4];   // [nj][mi], transposed D
#pragma unroll
    for (int nj = 0; nj < 4; ++nj)
#pragma unroll
        for (int mi = 0; mi < 4; ++mi) acc[nj][mi] = fz;
    const bf16* Ablk = A + (size_t)m0 * K;
    const bf16* Bblk = B + (size_t)n0 * K;

    // staging lane map: 16 rows per wave-issue, 4 chunks(16B)/row
    int srow = lane >> 2;              // 0..15
    int c    = lane & 3;

    // prologue: stage k0=0 into buf 0
#pragma unroll
    for (int i = 0; i < 2; ++i) {
        int r0 = i * 64 + wave * 16;
        int row = r0 + srow;
        int sc = (c ^ (row & 3)) << 3;
        GLOAD_LDS16(&Ablk[(size_t)row * K + sc], &SMEM[r0 * 32]);
        GLOAD_LDS16(&Bblk[(size_t)row * K + sc], &SMEM[4096 + r0 * 32]);
    }

    int p = 0;
    for (int k0 = 0; k0 < K; k0 += 32) {
        __syncthreads();   // drains async loads into buf[p]; syncs block

        if (k0 + 32 < K) {   // prefetch next tile into buf[1-p]
            int kn = k0 + 32;
#pragma unroll
            for (int i = 0; i < 2; ++i) {
                int r0 = i * 64 + wave * 16;
                int row = r0 + srow;
                int sc = (c ^ (row & 3)) << 3;
                GLOAD_LDS16(&Ablk[(size_t)row * K + kn + sc],
                            &SMEM[(1 - p) * 8192 + r0 * 32]);
                GLOAD_LDS16(&Bblk[(size_t)row * K + kn + sc],
                            &SMEM[4096 + (1 - p) * 8192 + r0 * 32]);
            }
        }

        const bf16* Asp = &SMEM[p * 8192];
        const bf16* Bsp = &SMEM[4096 + p * 8192];
        bf16x8 af[4], bfv[4];
#pragma unroll
        for (int t = 0; t < 4; ++t) {
            af[t]  = *(const bf16x8*)&Asp[SW32(wr * 64 + t * 16 + l16, quad)];
            bfv[t] = *(const bf16x8*)&Bsp[SW32(wc * 64 + t * 16 + l16, quad)];
        }
#pragma unroll
        for (int nj = 0; nj < 4; ++nj)
#pragma unroll
            for (int mi = 0; mi < 4; ++mi)
                acc[nj][mi] = MFMA16(bfv[nj], af[mi], acc[nj][mi]);
        p ^= 1;
    }

    // ---- Epilogue: acc -> LDS tile -> coalesced global stores (v4) ----
    int which = n0 / 768;
    int h0 = (n0 % 768) >> 6;
    int b = m0 >> 11, l0 = m0 & 2047;
    __syncthreads();

    if (which == 2) {
#pragma unroll
        for (int nj = 0; nj < 4; ++nj) {
            int cl0 = wc * 64 + nj * 16 + quad * 4;
            float4 bv4 = *(const float4*)&bias[n0 + cl0];
            float bv[4] = {bv4.x, bv4.y, bv4.z, bv4.w};
#pragma unroll
            for (int mi = 0; mi < 4; ++mi) {
                int xrl = wr * 64 + mi * 16 + l16;
#pragma unroll
                for (int r = 0; r < 4; ++r)
                    SMEM[(cl0 + r) * CLD + xrl] = (bf16)(acc[nj][mi][r] + bv[r]);
            }
        }
    } else {
        float s = (which == 0) ? 0.125f : 1.0f;
#pragma unroll
        for (int nj = 0; nj < 4; ++nj) {
            int cl0 = wc * 64 + nj * 16 + quad * 4;
            float4 bv4 = *(const float4*)&bias[n0 + cl0];
            float bv[4] = {bv4.x, bv4.y, bv4.z, bv4.w};
#pragma unroll
            for (int mi = 0; mi < 4; ++mi) {
                int xrl = wr * 64 + mi * 16 + l16;
                bf16x4 v;
#pragma unroll
                for (int r = 0; r < 4; ++r) v[r] = (bf16)((acc[nj][mi][r] + bv[r]) * s);
                *(bf16x4*)&SMEM[xrl * CLD + cl0] = v;
            }
        }
    }
    __syncthreads();

    if (which == 2) {
#pragma unroll
        for (int i = 0; i < 8; ++i) {
            int idx = i * 256 + tid;
            int cl = idx >> 4, ch = idx & 15;
            int d = cl & 63, h = h0 + (cl >> 6);
            bf16x8 v = *(const bf16x8*)&SMEM[cl * CLD + ch * 8];
            *(bf16x8*)&Vth[((size_t)(b * 12 + h) * 64 + d) * 2048 + l0 + ch * 8] = v;
        }
    } else {
        bf16* dst = (which == 0) ? Qh : Kh;
#pragma unroll
        for (int i = 0; i < 8; ++i) {
            int idx = i * 256 + tid;
            int rr = idx >> 4, ch = idx & 15;
            int h = h0 + (ch >> 3), d0 = (ch & 7) * 8;
            bf16x8 v = *(const bf16x8*)&SMEM[rr * CLD + ch * 8];
            *(bf16x8*)&dst[((size_t)(b * 12 + h) * 2048 + l0 + rr) * 64 + d0] = v;
        }
    }
}

// ---------------------------------------------------------------------------
// Out-projection GEMM v4: BK=32 double-buffered single-barrier K-loop.
// 128M x 64N tiles, 128 thr, grid (12, 32). out(F32) = ctx @ woutT^T + b_out.
// ---------------------------------------------------------------------------
__global__ __launch_bounds__(128) void gemm_out_v4(
    const bf16* __restrict__ A, const bf16* __restrict__ B,
    const float* __restrict__ bias, float* __restrict__ C) {
    __shared__ __align__(16) bf16 As[2][128 * 32];   // 16 KB
    __shared__ __align__(16) bf16 Bs[2][64 * 32];    //  8 KB
    int tid = threadIdx.x, lane = tid & 63, wave = tid >> 6;  // wave 0..1
    int quad = lane >> 4, l16 = lane & 15;
    int m0 = blockIdx.y * 128, n0 = blockIdx.x * 64;
    const int K = 768, N = 768;
    const f32x4 fz = {0.f, 0.f, 0.f, 0.f};
    f32x4 acc[4][4];
#pragma unroll
    for (int mi = 0; mi < 4; ++mi)
#pragma unroll
        for (int nj = 0; nj < 4; ++nj) acc[mi][nj] = fz;
    const bf16* Ablk = A + (size_t)m0 * K;
    const bf16* Bblk = B + (size_t)n0 * K;
    int srow = lane >> 2, c = lane & 3;

    // prologue: stage k0=0 into buf 0
#pragma unroll
    for (int i = 0; i < 4; ++i) {
        int r0 = i * 32 + wave * 16;
        int row = r0 + srow;
        int sc = (c ^ (row & 3)) << 3;
        GLOAD_LDS16(&Ablk[(size_t)row * K + sc], &As[0][r0 * 32]);
    }
#pragma unroll
    for (int i = 0; i < 2; ++i) {
        int r0 = i * 32 + wave * 16;
        int row = r0 + srow;
        int sc = (c ^ (row & 3)) << 3;
        GLOAD_LDS16(&Bblk[(size_t)row * K + sc], &Bs[0][r0 * 32]);
    }

    int p = 0;
    for (int k0 = 0; k0 < K; k0 += 32) {
        __syncthreads();

        if (k0 + 32 < K) {
            int kn = k0 + 32;
#pragma unroll
            for (int i = 0; i < 4; ++i) {
                int r0 = i * 32 + wave * 16;
                int row = r0 + srow;
                int sc = (c ^ (row & 3)) << 3;
                GLOAD_LDS16(&Ablk[(size_t)row * K + kn + sc], &As[1 - p][r0 * 32]);
            }
#pragma unroll
            for (int i = 0; i < 2; ++i) {
                int r0 = i * 32 + wave * 16;
                int row = r0 + srow;
                int sc = (c ^ (row & 3)) << 3;
                GLOAD_LDS16(&Bblk[(size_t)row * K + kn + sc], &Bs[1 - p][r0 * 32]);
            }
        }

        bf16x8 af[4], bfv[4];
#pragma unroll
        for (int t = 0; t < 4; ++t) {
            af[t]  = *(const bf16x8*)&As[p][SW32(wave * 64 + t * 16 + l16, quad)];
            bfv[t] = *(const bf16x8*)&Bs[p][SW32(t * 16 + l16, quad)];
        }
#pragma unroll
        for (int mi = 0; mi < 4; ++mi)
#pragma unroll
            for (int nj = 0; nj < 4; ++nj)
                acc[mi][nj] = MFMA16(af[mi], bfv[nj], acc[mi][nj]);
        p ^= 1;
    }

#pragma unroll
    for (int nj = 0; nj < 4; ++nj) {
        int col = n0 + nj * 16 + l16;
        float bv = bias[col];
#pragma unroll
        for (int mi = 0; mi < 4; ++mi)
#pragma unroll
            for (int r = 0; r < 4; ++r) {
                int row = m0 + wave * 64 + mi * 16 + quad * 4 + r;
                C[(size_t)row * N + col] = acc[mi][nj][r] + bv;
            }
    }
}

// ---------------------------------------------------------------------------
// Flash attention v6 (unchanged from R17: 80.2 us).
// ---------------------------------------------------------------------------
#define PLD 72

__global__ __launch_bounds__(256) void flash_attn(
    const bf16* __restrict__ Q, const bf16* __restrict__ K,
    const bf16* __restrict__ V, const int* __restrict__ mask,
    bf16* __restrict__ ctx) {
    __shared__ __align__(16) bf16 Ks[2][64 * 64];
    __shared__ __align__(16) bf16 Vs[2][64 * 64];
    __shared__ __align__(16) bf16 Ps[4][16 * PLD];
    __shared__ float maskS[2048];
    __shared__ int cleanF;

    int tid = threadIdx.x, lane = tid & 63, wave = tid >> 6;
    int quad = lane >> 4, l16 = lane & 15;
    int bh = blockIdx.y, b = bh / 12;
    int q0 = blockIdx.x * 128 + wave * 32;

    bf16x8 aq[2][2];
#pragma unroll
    for (int qt = 0; qt < 2; ++qt) {
        const bf16* Qp = Q + ((size_t)bh * 2048 + q0 + qt * 16 + l16) * 64;
        aq[qt][0] = *(const bf16x8*)(Qp + quad * 8);
        aq[qt][1] = *(const bf16x8*)(Qp + 32 + quad * 8);
    }

    if (tid == 0) cleanF = 1;
    __syncthreads();
    const int* mrow = mask + b * 2048;
    int myclean = 1;
#pragma unroll
    for (int i = 0; i < 8; ++i) {
        int idx = i * 256 + tid;
        int mv = mrow[idx];
        maskS[idx] = mv ? 0.0f : NEG_BIG;
        myclean &= (mv != 0);
    }
    if (!myclean) cleanF = 0;

    const f32x4 fz = {0.f, 0.f, 0.f, 0.f};
    f32x4 o[2][4];
    float m_i[2], l_i[2];
#pragma unroll
    for (int qt = 0; qt < 2; ++qt) {
        m_i[qt] = NEG_BIG; l_i[qt] = 0.f;
#pragma unroll
        for (int dt = 0; dt < 4; ++dt) o[qt][dt] = fz;
    }

    int srow = tid >> 3;
    int sc8  = (tid & 7) * 8;
    const bf16* Kbase = K + (size_t)bh * 2048 * 64;
    const bf16* Vbase = V + (size_t)bh * 64 * 2048;

#pragma unroll
    for (int i = 0; i < 2; ++i) {
        int row = srow + i * 32;
        *(bf16x8*)&Ks[0][SW(row, sc8)] =
            *(const bf16x8*)&Kbase[(size_t)row * 64 + sc8];
        *(bf16x8*)&Vs[0][SW(row, sc8)] =
            *(const bf16x8*)&Vbase[(size_t)row * 2048 + sc8];
    }
    __syncthreads();
    int clean = cleanF;

    int p = 0;
    for (int kb = 0; kb < 2048; kb += 64) {
        __syncthreads();

        if (kb + 64 < 2048) {
            int nb = kb + 64;
#pragma unroll
            for (int i = 0; i < 2; ++i) {
                int row = srow + i * 32;
                *(bf16x8*)&Ks[1 - p][SW(row, sc8)] =
                    *(const bf16x8*)&Kbase[(size_t)(nb + row) * 64 + sc8];
                *(bf16x8*)&Vs[1 - p][SW(row, sc8)] =
                    *(const bf16x8*)&Vbase[(size_t)row * 2048 + nb + sc8];
            }
        }

        f32x4 s[2][4];
#pragma unroll
        for (int ct = 0; ct < 4; ++ct) {
            int krow = ct * 16 + l16;
            bf16x8 kf0 = *(const bf16x8*)&Ks[p][SW(krow, quad * 8)];
            bf16x8 kf1 = *(const bf16x8*)&Ks[p][SW(krow, 32 + quad * 8)];
#pragma unroll
            for (int qt = 0; qt < 2; ++qt) {
                f32x4 t = fz;
                t = MFMA16(kf0, aq[qt][0], t);
                t = MFMA16(kf1, aq[qt][1], t);
                s[qt][ct] = t;
            }
        }

        if (!clean) {
#pragma unroll
            for (int ct = 0; ct < 4; ++ct) {
                const float* mk = &maskS[kb + ct * 16 + quad * 4];
                float4 mv = *(const float4*)mk;
                float ma[4] = {mv.x, mv.y, mv.z, mv.w};
#pragma unroll
                for (int qt = 0; qt < 2; ++qt)
#pragma unroll
                    for (int r = 0; r < 4; ++r) s[qt][ct][r] += ma[r];
            }
        }

        float alpha[2];
#pragma unroll
        for (int qt = 0; qt < 2; ++qt) {
            float mx = NEG_BIG;
#pragma unroll
            for (int ct = 0; ct < 4; ++ct)
#pragma unroll
                for (int r = 0; r < 4; ++r) mx = fmaxf(mx, s[qt][ct][r]);
            mx = fmaxf(mx, __shfl_xor(mx, 16));
            mx = fmaxf(mx, __shfl_xor(mx, 32));
            float nm = fmaxf(m_i[qt], mx);
            alpha[qt] = __expf(m_i[qt] - nm);
            m_i[qt] = nm;
            float sum = 0.f;
#pragma unroll
            for (int ct = 0; ct < 4; ++ct)
#pragma unroll
                for (int r = 0; r < 4; ++r) {
                    float pv = __expf(s[qt][ct][r] - nm);
                    s[qt][ct][r] = pv;
                    sum += pv;
                }
            sum += __shfl_xor(sum, 16);
            sum += __shfl_xor(sum, 32);
            l_i[qt] = l_i[qt] * alpha[qt] + sum;
        }

#pragma unroll
        for (int qt = 0; qt < 2; ++qt) {
            float ab[4];
#pragma unroll
            for (int r = 0; r < 4; ++r)
                ab[r] = __shfl(alpha[qt], (lane & 48) | (quad * 4 + r));
#pragma unroll
            for (int dt = 0; dt < 4; ++dt)
#pragma unroll
                for (int r = 0; r < 4; ++r) o[qt][dt][r] *= ab[r];
        }

        bf16x8 vf[2][4];
#pragma unroll
        for (int ks = 0; ks < 2; ++ks)
#pragma unroll
            for (int dt = 0; dt < 4; ++dt)
                vf[ks][dt] = *(const bf16x8*)&Vs[p][SW(dt * 16 + l16, ks * 32 + quad * 8)];

#pragma unroll
        for (int qt = 0; qt < 2; ++qt) {
#pragma unroll
            for (int ct = 0; ct < 4; ++ct) {
                bf16x4 pk;
#pragma unroll
                for (int r = 0; r < 4; ++r) pk[r] = (bf16)s[qt][ct][r];
                *(bf16x4*)&Ps[wave][l16 * PLD + ct * 16 + quad * 4] = pk;
            }
#pragma unroll
            for (int ks = 0; ks < 2; ++ks) {
                bf16x8 ap = *(const bf16x8*)&Ps[wave][l16 * PLD + ks * 32 + quad * 8];
#pragma unroll
                for (int dt = 0; dt < 4; ++dt)
                    o[qt][dt] = MFMA16(ap, vf[ks][dt], o[qt][dt]);
            }
        }
        p ^= 1;
    }

    int h = bh % 12;
#pragma unroll
    for (int qt = 0; qt < 2; ++qt) {
        float linv[4];
#pragma unroll
        for (int r = 0; r < 4; ++r)
            linv[r] = 1.0f / __shfl(l_i[qt], (lane & 48) | (quad * 4 + r));
#pragma unroll
        for (int dt = 0; dt < 4; ++dt)
#pragma unroll
            for (int r = 0; r < 4; ++r) {
                int qrow = q0 + qt * 16 + quad * 4 + r;
                ctx[((size_t)b * 2048 + qrow) * 768 + h * 64 + dt * 16 + l16] =
                    (bf16)(o[qt][dt][r] * linv[r]);
            }
    }
}

// ---------------------------------------------------------------------------
extern "C" void kernel_launch(void* const* d_in, const int* in_sizes, int n_in,
                              void* d_out, int out_size, void* d_ws, size_t ws_size,
                              hipStream_t stream) {
    float* out = (float*)d_out;

    const float* x = nullptr; const int* mask = nullptr;
    const float* w_qkv = nullptr; const float* b_qkv = nullptr;
    const float* w_out = nullptr; const float* b_out = nullptr;
    int found = 0;
    for (int i = 0; i < n_in; ++i) {
        switch (in_sizes[i]) {
            case 3145728: x     = (const float*)d_in[i]; found |= 1;  break;
            case 4096:    mask  = (const int*)  d_in[i]; found |= 2;  break;
            case 1769472: w_qkv = (const float*)d_in[i]; found |= 4;  break;
            case 2304:    b_qkv = (const float*)d_in[i]; found |= 8;  break;
            case 589824:  w_out = (const float*)d_in[i]; found |= 16; break;
            case 768:     b_out = (const float*)d_in[i]; found |= 32; break;
        }
    }
    if (found != 63) {
        mark_k<<<(out_size + 255) / 256, 256, 0, stream>>>(
            out, 200.0f + (float)found, out_size);
        return;
    }

    const int M = 4096, D = 768, N3 = 2304;
    const size_t HEADS_ELEMS = (size_t)24 * 2048 * 64;

    bf16* ws    = (bf16*)d_ws;
    bf16* Kh    = ws;
    bf16* Vth   = Kh + HEADS_ELEMS;
    bf16* ctx   = Vth + HEADS_ELEMS;
    bf16* wqkvT = ctx + (size_t)M * D;
    bf16* woutT = wqkvT + (size_t)N3 * D;
    bf16* Qh    = (bf16*)d_out;
    bf16* xb    = (bf16*)d_out + HEADS_ELEMS;

    cvt_x_k<<<(M * D / 8 + 255) / 256, 256, 0, stream>>>(x, xb, M * D);
    transpose_cvt_tiled<<<dim3(2304 / 32, 768 / 32), 256, 0, stream>>>(
        w_qkv, wqkvT, 768, 2304);
    transpose_cvt_tiled<<<dim3(768 / 32, 768 / 32), 256, 0, stream>>>(
        w_out, woutT, 768, 768);

    gemm_qkv_v5<<<dim3(N3 / 128, M / 128), 256, 0, stream>>>(
        xb, wqkvT, b_qkv, Qh, Kh, Vth);

    flash_attn<<<dim3(2048 / 128, 24), 256, 0, stream>>>(Qh, Kh, Vth, mask, ctx);

    gemm_out_v4<<<dim3(D / 64, M / 128), 128, 0, stream>>>(
        ctx, woutT, b_out, out);
}